// Round 1
// baseline (816.522 us; speedup 1.0000x reference)
//
#include <hip/hip_runtime.h>
#include <hip/hip_bf16.h>

// AddIdentityTLUT: elementwise
//   addr  = x * 2^-shamt
//   large = addr > 0
//   rem   = (x*2) * alpha
//   mixed = large ? addr : rem          (== addr*is_large + rem*is_small)
//   y     = log2(mixed)
//   out   = large ? y : y + falpha      (== y + falpha*is_small)
// Memory-bound: 1 GiB traffic for 128Mi f32 elems. float4 loads/stores.

__global__ __launch_bounds__(256) void addid_tlut_kernel(
    const float* __restrict__ x,
    float* __restrict__ out,
    const float* __restrict__ alpha_p,
    const float* __restrict__ falpha_p,
    const int* __restrict__ shamt_p,
    long long n)
{
    const float alpha  = *alpha_p;
    const float falpha = *falpha_p;
    const int   shamt  = *shamt_p;
    const float scale  = exp2f((float)(-shamt));   // 2^-shamt

    long long i4   = (long long)blockIdx.x * blockDim.x + threadIdx.x;
    long long base = i4 * 4;
    if (base >= n) return;

    if (base + 3 < n) {
        // vector path
        float4 v = *reinterpret_cast<const float4*>(x + base);
        float4 r;
        {
            float xv = v.x;
            float addr = xv * scale;
            bool large = addr > 0.0f;
            float mixed = large ? addr : (xv * 2.0f) * alpha;
            float y = __log2f(mixed);
            r.x = large ? y : y + falpha;
        }
        {
            float xv = v.y;
            float addr = xv * scale;
            bool large = addr > 0.0f;
            float mixed = large ? addr : (xv * 2.0f) * alpha;
            float y = __log2f(mixed);
            r.y = large ? y : y + falpha;
        }
        {
            float xv = v.z;
            float addr = xv * scale;
            bool large = addr > 0.0f;
            float mixed = large ? addr : (xv * 2.0f) * alpha;
            float y = __log2f(mixed);
            r.z = large ? y : y + falpha;
        }
        {
            float xv = v.w;
            float addr = xv * scale;
            bool large = addr > 0.0f;
            float mixed = large ? addr : (xv * 2.0f) * alpha;
            float y = __log2f(mixed);
            r.w = large ? y : y + falpha;
        }
        *reinterpret_cast<float4*>(out + base) = r;
    } else {
        // scalar tail
        for (long long j = base; j < n; ++j) {
            float xv = x[j];
            float addr = xv * scale;
            bool large = addr > 0.0f;
            float mixed = large ? addr : (xv * 2.0f) * alpha;
            float y = __log2f(mixed);
            out[j] = large ? y : y + falpha;
        }
    }
}

extern "C" void kernel_launch(void* const* d_in, const int* in_sizes, int n_in,
                              void* d_out, int out_size, void* d_ws, size_t ws_size,
                              hipStream_t stream) {
    const float* x        = (const float*)d_in[0];
    const float* alpha_p  = (const float*)d_in[1];
    const float* falpha_p = (const float*)d_in[2];
    const int*   shamt_p  = (const int*)d_in[3];
    float* out = (float*)d_out;

    long long n = (long long)in_sizes[0];
    long long n4 = (n + 3) / 4;                 // one thread per float4
    int block = 256;
    long long grid = (n4 + block - 1) / block;

    addid_tlut_kernel<<<(dim3)(unsigned)grid, block, 0, stream>>>(
        x, out, alpha_p, falpha_p, shamt_p, n);
}